// Round 1
// baseline (128.671 us; speedup 1.0000x reference)
//
#include <hip/hip_runtime.h>
#include <hip/hip_cooperative_groups.h>

namespace cg = cooperative_groups;

// CrossModalCenterLoss collapses analytically:
//   dist = distmat * one_hot(labels)  -> only distmat[b, labels[b]] survives;
//   clip(0, 1e-12, 1e12) = 1e-12 for the B*(C-1) masked entries.
//   loss = mean_b clip(||x_b - centers[l_b]||^2) + (C-1)*1e-12
// ~8 MB of real traffic. Previous version spent the residual time on TWO
// kernel dispatches; this version fuses them with a cooperative grid sync.
// The reduction tree is kept bit-identical to the 2-kernel version
// (per-row wave shuffle -> sm[0..3] -> partial[block]; then
//  p[i]+p[i+256]+p[i+512]+p[i+768] -> wave shuffle -> sm2[0..3]).

#define BATCH      4096
#define FEAT_DIM   256
#define NUM_CLS    10000
#define CLAMP_MIN_F 1e-12f
#define CLAMP_MAX_F 1e12f

__global__ __launch_bounds__(256) void cmcl_fused(
    const float* __restrict__ x,
    const int*   __restrict__ labels,
    const float* __restrict__ centers,
    float*       __restrict__ partial,   // [1024] in d_ws
    float*       __restrict__ out)
{
    const int lane = threadIdx.x & 63;
    const int wave = threadIdx.x >> 6;
    const int row  = (blockIdx.x << 2) + wave;   // 1024 blocks * 4 rows = 4096

    const int label = labels[row];
    const float4* __restrict__ xr = (const float4*)(x       + (size_t)row   * FEAT_DIM);
    const float4* __restrict__ cr = (const float4*)(centers + (size_t)label * FEAT_DIM);

    // 64 lanes * 4 floats = 256 = FEAT_DIM, one float4 per lane.
    float4 xv = xr[lane];
    float4 cv = cr[lane];
    float dx = xv.x - cv.x;
    float dy = xv.y - cv.y;
    float dz = xv.z - cv.z;
    float dw = xv.w - cv.w;
    float v = dx*dx + dy*dy + dz*dz + dw*dw;

    // wave-64 shuffle reduction (identical order to previous version)
    #pragma unroll
    for (int off = 32; off > 0; off >>= 1)
        v += __shfl_down(v, off, 64);

    __shared__ float sm[4];
    if (lane == 0) {
        // clamp applied per masked element (the surviving diagonal entry)
        v = fminf(fmaxf(v, CLAMP_MIN_F), CLAMP_MAX_F);
        sm[wave] = v;
    }
    __syncthreads();
    if (threadIdx.x == 0) {
        partial[blockIdx.x] = sm[0] + sm[1] + sm[2] + sm[3];
        __threadfence();   // device-scope: make partial visible across XCDs
    }

    // ---- grid-wide barrier, then block 0 does the final reduction ----
    cg::this_grid().sync();

    if (blockIdx.x == 0) {
        float r = partial[threadIdx.x]
                + partial[threadIdx.x + 256]
                + partial[threadIdx.x + 512]
                + partial[threadIdx.x + 768];

        #pragma unroll
        for (int off = 32; off > 0; off >>= 1)
            r += __shfl_down(r, off, 64);

        __shared__ float sm2[4];
        if (lane == 0) sm2[wave] = r;
        __syncthreads();
        if (threadIdx.x == 0) {
            float total = sm2[0] + sm2[1] + sm2[2] + sm2[3];
            // + clamp-floor contribution of the (C-1) masked zeros per row:
            // B*(C-1)*1e-12 / B = (C-1)*1e-12
            out[0] = total / (float)BATCH + (float)(NUM_CLS - 1) * CLAMP_MIN_F;
        }
    }
}

extern "C" void kernel_launch(void* const* d_in, const int* in_sizes, int n_in,
                              void* d_out, int out_size, void* d_ws, size_t ws_size,
                              hipStream_t stream) {
    const float* x       = (const float*)d_in[0];
    const int*   labels  = (const int*)  d_in[1];
    const float* centers = (const float*)d_in[2];
    float*       out     = (float*)d_out;
    float*       partial = (float*)d_ws;   // 1024 floats = 4 KB

    void* args[] = { (void*)&x, (void*)&labels, (void*)&centers,
                     (void*)&partial, (void*)&out };
    hipLaunchCooperativeKernel((void*)cmcl_fused,
                               dim3(BATCH / 4), dim3(256),
                               args, 0, stream);
}

// Round 2
// 93.714 us; speedup vs baseline: 1.3730x; 1.3730x over previous
//
#include <hip/hip_runtime.h>

// CrossModalCenterLoss collapses analytically:
//   dist = distmat * one_hot(labels)  -> only distmat[b, labels[b]] survives;
//   clip(0, 1e-12, 1e12) = 1e-12 for the B*(C-1) masked entries.
//   loss = mean_b clip(||x_b - centers[l_b]||^2) + (C-1)*1e-12
//
// Round-1 post-mortem: cg grid sync = 50 us multi-XCD spin barrier. Replaced
// with LAST-BLOCK-DONE: no block waits; the last block to finish (detected via
// device-scope atomic counter) performs the final reduction with the SAME
// summation tree as the original 2-kernel version -> bit-identical output.
// Counter is zeroed by a 4-byte hipMemsetAsync node (ws is re-poisoned every
// iteration by the harness).

#define BATCH      4096
#define FEAT_DIM   256
#define NUM_CLS    10000
#define NBLOCKS    (BATCH / 4)          // 1024
#define CLAMP_MIN_F 1e-12f
#define CLAMP_MAX_F 1e12f

__global__ __launch_bounds__(256) void cmcl_fused_lb(
    const float* __restrict__ x,
    const int*   __restrict__ labels,
    const float* __restrict__ centers,
    float*        partial,              // ws + 0      : 1024 floats
    unsigned int* counter,              // ws + 4096   : 1 u32 (memset to 0)
    float*       __restrict__ out)
{
    const int lane = threadIdx.x & 63;
    const int wave = threadIdx.x >> 6;
    const int row  = (blockIdx.x << 2) + wave;   // 1024 blocks * 4 rows = 4096

    const int label = labels[row];
    const float4* __restrict__ xr = (const float4*)(x       + (size_t)row   * FEAT_DIM);
    const float4* __restrict__ cr = (const float4*)(centers + (size_t)label * FEAT_DIM);

    // 64 lanes * 4 floats = 256 = FEAT_DIM, one float4 per lane.
    float4 xv = xr[lane];
    float4 cv = cr[lane];
    float dx = xv.x - cv.x;
    float dy = xv.y - cv.y;
    float dz = xv.z - cv.z;
    float dw = xv.w - cv.w;
    float v = dx*dx + dy*dy + dz*dz + dw*dw;

    // wave-64 shuffle reduction (identical order to round-0 version)
    #pragma unroll
    for (int off = 32; off > 0; off >>= 1)
        v += __shfl_down(v, off, 64);

    __shared__ float sm[4];
    __shared__ int   is_last;
    if (lane == 0) {
        // clamp applied per masked element (the surviving diagonal entry)
        v = fminf(fmaxf(v, CLAMP_MIN_F), CLAMP_MAX_F);
        sm[wave] = v;
    }
    __syncthreads();

    if (threadIdx.x == 0) {
        float bs = sm[0] + sm[1] + sm[2] + sm[3];
        // release-store partial at agent (device) scope, then acq_rel ticket.
        // The RMW chain carries happens-before from every block's store to
        // the finisher's acquire.
        __hip_atomic_store(&partial[blockIdx.x], bs,
                           __ATOMIC_RELEASE, __HIP_MEMORY_SCOPE_AGENT);
        unsigned int old = __hip_atomic_fetch_add(counter, 1u,
                           __ATOMIC_ACQ_REL, __HIP_MEMORY_SCOPE_AGENT);
        is_last = (old == (unsigned int)(NBLOCKS - 1));
    }
    __syncthreads();     // broadcast is_last; no cross-block waiting anywhere

    if (is_last) {
        // Final reduction: same tree as the old cmcl_reduce kernel.
        // Agent-scope loads bypass potentially-stale per-XCD caches.
        const int t = threadIdx.x;
        float r = __hip_atomic_load(&partial[t      ], __ATOMIC_RELAXED, __HIP_MEMORY_SCOPE_AGENT)
                + __hip_atomic_load(&partial[t + 256], __ATOMIC_RELAXED, __HIP_MEMORY_SCOPE_AGENT)
                + __hip_atomic_load(&partial[t + 512], __ATOMIC_RELAXED, __HIP_MEMORY_SCOPE_AGENT)
                + __hip_atomic_load(&partial[t + 768], __ATOMIC_RELAXED, __HIP_MEMORY_SCOPE_AGENT);

        #pragma unroll
        for (int off = 32; off > 0; off >>= 1)
            r += __shfl_down(r, off, 64);

        __shared__ float sm2[4];
        if (lane == 0) sm2[wave] = r;
        __syncthreads();
        if (threadIdx.x == 0) {
            float total = sm2[0] + sm2[1] + sm2[2] + sm2[3];
            // + clamp-floor contribution of the (C-1) masked zeros per row:
            // B*(C-1)*1e-12 / B = (C-1)*1e-12
            out[0] = total / (float)BATCH + (float)(NUM_CLS - 1) * CLAMP_MIN_F;
        }
    }
}

extern "C" void kernel_launch(void* const* d_in, const int* in_sizes, int n_in,
                              void* d_out, int out_size, void* d_ws, size_t ws_size,
                              hipStream_t stream) {
    const float* x       = (const float*)d_in[0];
    const int*   labels  = (const int*)  d_in[1];
    const float* centers = (const float*)d_in[2];
    float*       out     = (float*)d_out;

    float*        partial = (float*)d_ws;                       // 4 KB
    unsigned int* counter = (unsigned int*)((char*)d_ws + 4096);

    // ws is re-poisoned every iteration -> zero the ticket counter (4 bytes).
    hipMemsetAsync(counter, 0, sizeof(unsigned int), stream);

    cmcl_fused_lb<<<NBLOCKS, 256, 0, stream>>>(x, labels, centers,
                                               partial, counter, out);
}

// Round 3
// 64.654 us; speedup vs baseline: 1.9902x; 1.4495x over previous
//
#include <hip/hip_runtime.h>

// CrossModalCenterLoss collapses analytically:
//   dist = distmat * one_hot(labels)  -> only distmat[b, labels[b]] survives;
//   clip(0, 1e-12, 1e12) = 1e-12 for the B*(C-1) masked entries.
//   loss = mean_b clip(||x_b - centers[l_b]||^2) + (C-1)*1e-12
//
// Round-1 post-mortem: cg grid sync = 50 us multi-XCD spin barrier. BAD.
// Round-2 post-mortem: agent-scope ACQ_REL atomics x1024 blocks = per-block
//   L2 writeback/invalidate (gfx950 XCD L2s non-coherent) = ~30 us hidden. BAD.
// Round-3: ONE kernel node, no memset, no fences, no ordered atomics.
//   Each block publishes its partial as a self-validating {bits, bits^MAGIC}
//   8-byte pair via a RELAXED agent-scope atomic store (sc1 -> coherent point,
//   no cache maintenance). Block 0 polls the pairs with relaxed agent-scope
//   atomic loads (also coherent-point, stale-proof) and finishes with the
//   SAME reduction tree as the original 2-kernel version -> bit-identical.
//   Poison safety: a constant/random ws fill cannot satisfy hi == lo^MAGIC
//   except in coincidence cases where the extracted value equals the true
//   partial anyway (proof in comments below).

#define BATCH      4096
#define FEAT_DIM   256
#define NUM_CLS    10000
#define NBLOCKS    (BATCH / 4)          // 1024
#define CLAMP_MIN_F 1e-12f
#define CLAMP_MAX_F 1e12f
#define MAGIC      0xA5A5A5A5u

__global__ __launch_bounds__(256) void cmcl_onenode(
    const float* __restrict__ x,
    const int*   __restrict__ labels,
    const float* __restrict__ centers,
    unsigned long long* pairs,          // ws: 1024 x u64 = 8 KB
    float*       __restrict__ out)
{
    const int lane = threadIdx.x & 63;
    const int wave = threadIdx.x >> 6;
    const int row  = (blockIdx.x << 2) + wave;   // 1024 blocks * 4 rows = 4096

    const int label = labels[row];
    const float4* __restrict__ xr = (const float4*)(x       + (size_t)row   * FEAT_DIM);
    const float4* __restrict__ cr = (const float4*)(centers + (size_t)label * FEAT_DIM);

    // 64 lanes * 4 floats = 256 = FEAT_DIM, one float4 per lane.
    float4 xv = xr[lane];
    float4 cv = cr[lane];
    float dx = xv.x - cv.x;
    float dy = xv.y - cv.y;
    float dz = xv.z - cv.z;
    float dw = xv.w - cv.w;
    float v = dx*dx + dy*dy + dz*dz + dw*dw;

    // wave-64 shuffle reduction (identical order to round-0 version)
    #pragma unroll
    for (int off = 32; off > 0; off >>= 1)
        v += __shfl_down(v, off, 64);

    __shared__ float sm[4];
    if (lane == 0) {
        // clamp applied per masked element (the surviving diagonal entry)
        v = fminf(fmaxf(v, CLAMP_MIN_F), CLAMP_MAX_F);
        sm[wave] = v;
    }
    __syncthreads();

    if (threadIdx.x == 0) {
        float bs = sm[0] + sm[1] + sm[2] + sm[3];
        unsigned int b = __float_as_uint(bs);
        unsigned long long p = (unsigned long long)b
                             | ((unsigned long long)(b ^ MAGIC) << 32);
        // RELAXED agent-scope 64-bit atomic store: sc1 path straight to the
        // coherent point. No release fence -> no buffer_wbl2 -> cheap.
        __hip_atomic_store(&pairs[blockIdx.x], p,
                           __ATOMIC_RELAXED, __HIP_MEMORY_SCOPE_AGENT);
    }

    if (blockIdx.x != 0) return;   // everyone else is done; no waiting

    // ---- finisher: block 0 polls all 1024 self-validating pairs ----
    // Safety of the check (poison = P, true value = v):
    //   pair fully new:            hi == lo^MAGIC, value = v.        correct
    //   lo stale P, hi new:        passes iff P == v -> value = P = v. correct
    //   lo new v, hi stale Q:      passes iff Q == v^MAGIC -> value = v. correct
    // In every passing case the extracted value is bit-equal to v.
    const int t = threadIdx.x;
    float vals[4];
    #pragma unroll
    for (int k = 0; k < 4; ++k) {
        const int idx = t + (k << 8);          // t, t+256, t+512, t+768
        unsigned long long p;
        do {
            p = __hip_atomic_load(&pairs[idx],
                                  __ATOMIC_RELAXED, __HIP_MEMORY_SCOPE_AGENT);
        } while ((unsigned int)(p >> 32) != ((unsigned int)p ^ MAGIC));
        vals[k] = __uint_as_float((unsigned int)p);
    }
    // same 4-term chain order as the old cmcl_reduce kernel
    float r = vals[0] + vals[1] + vals[2] + vals[3];

    #pragma unroll
    for (int off = 32; off > 0; off >>= 1)
        r += __shfl_down(r, off, 64);

    __shared__ float sm2[4];
    if (lane == 0) sm2[wave] = r;
    __syncthreads();
    if (threadIdx.x == 0) {
        float total = sm2[0] + sm2[1] + sm2[2] + sm2[3];
        // + clamp-floor contribution of the (C-1) masked zeros per row:
        // B*(C-1)*1e-12 / B = (C-1)*1e-12
        out[0] = total / (float)BATCH + (float)(NUM_CLS - 1) * CLAMP_MIN_F;
    }
}

extern "C" void kernel_launch(void* const* d_in, const int* in_sizes, int n_in,
                              void* d_out, int out_size, void* d_ws, size_t ws_size,
                              hipStream_t stream) {
    const float* x       = (const float*)d_in[0];
    const int*   labels  = (const int*)  d_in[1];
    const float* centers = (const float*)d_in[2];
    float*       out     = (float*)d_out;
    unsigned long long* pairs = (unsigned long long*)d_ws;   // 8 KB

    cmcl_onenode<<<NBLOCKS, 256, 0, stream>>>(x, labels, centers, pairs, out);
}